// Round 9
// baseline (83.704 us; speedup 1.0000x reference)
//
#include <hip/hip_runtime.h>

typedef unsigned short u16;
typedef unsigned int u32;
typedef float f32x4 __attribute__((ext_vector_type(4)));
typedef short s16x8 __attribute__((ext_vector_type(8)));
typedef unsigned int u32x2 __attribute__((ext_vector_type(2)));
typedef unsigned int u32x4 __attribute__((ext_vector_type(4)));

#define NB 4
#define NT 4096
#define ND 128
#define NQ (NB * NT)

// (1/sqrt(128)) * log2(e)  -- folded into Q so softmax runs in exp2 domain
#define QK_SCALE 0.12751879523138906f

using as3_void = __attribute__((address_space(3))) void;
using as1_void = __attribute__((address_space(1))) void;

__device__ __forceinline__ u16 f2bf(float x){
  unsigned u = __float_as_uint(x);
  return (u16)((u + 0x7FFFu + ((u >> 16) & 1u)) >> 16);   // RNE
}
__device__ __forceinline__ u32 cvtpk(float lo, float hi){
  u32 r; asm("v_cvt_pk_bf16_f32 %0, %1, %2" : "=v"(r) : "v"(lo), "v"(hi)); return r;
}
__device__ __forceinline__ f32x4 mfma16(s16x8 a, s16x8 b, f32x4 c){
  return __builtin_amdgcn_mfma_f32_16x16x32_bf16(a, b, c, 0, 0, 0);
}

// ---------------- kernel 0: weights -> bf16, transposed wt[mat][f][c] ----------------
__global__ void k_wprep(const float* __restrict__ Wq, const float* __restrict__ Wk,
                        const float* __restrict__ Wv, u16* __restrict__ WT){
  int mat = blockIdx.x >> 7;
  int f   = blockIdx.x & 127;
  const float* W = (mat == 0) ? Wq : (mat == 1) ? Wk : Wv;
  int c = threadIdx.x;
  WT[mat * 16384 + f * 128 + c] = f2bf(W[c * 128 + f]);
}

// ---------------- kernel 1: QKV projection (R8-verified layouts) ----------------
// Qs : bf16 [NQ][128], scaled by QK_SCALE (row-major)
// Ks : bf16 [NQ][128], element (r,f) at col f ^ ((r&7)<<3)                 (b128-read swizzle)
// VTs: bf16 [B][128][N], (f,n) at col n ^ ((f&3)<<3) ^ (((f>>2)&1)<<2)     (b64-read swizzle)
__global__ __launch_bounds__(256) void k_proj(
    const float* __restrict__ X, const u16* __restrict__ WT,
    const float* __restrict__ bq, const float* __restrict__ bk, const float* __restrict__ bv,
    u16* __restrict__ Qs, u16* __restrict__ Ks, u16* __restrict__ VTs)
{
  const int lane = threadIdx.x & 63;
  const int w    = threadIdx.x >> 6;
  const int lm = lane & 15, lg = lane >> 4;
  const int rowbase = blockIdx.x * 64 + w * 16;

  s16x8 a[4];
  const float* xr = X + (rowbase + lm) * ND;
  #pragma unroll
  for (int kc = 0; kc < 4; ++kc){
    f32x4 x0 = *(const f32x4*)(xr + kc * 32 + lg * 8);
    f32x4 x1 = *(const f32x4*)(xr + kc * 32 + lg * 8 + 4);
    s16x8 t;
    t[0]=(short)f2bf(x0[0]); t[1]=(short)f2bf(x0[1]); t[2]=(short)f2bf(x0[2]); t[3]=(short)f2bf(x0[3]);
    t[4]=(short)f2bf(x1[0]); t[5]=(short)f2bf(x1[1]); t[6]=(short)f2bf(x1[2]); t[7]=(short)f2bf(x1[3]);
    a[kc] = t;
  }

  #pragma unroll
  for (int mat = 0; mat < 3; ++mat){
    const float* bias = (mat==0) ? bq : (mat==1) ? bk : bv;
    float bl[8];
    #pragma unroll
    for (int n = 0; n < 8; ++n) bl[n] = bias[n * 16 + lm];
    f32x4 acc[8];
    #pragma unroll
    for (int n = 0; n < 8; ++n) acc[n] = f32x4{0.f,0.f,0.f,0.f};
    #pragma unroll
    for (int kc = 0; kc < 4; ++kc){
      #pragma unroll
      for (int n = 0; n < 8; ++n){
        s16x8 bf = *(const s16x8*)&WT[mat*16384 + (n*16 + lm)*128 + kc*32 + lg*8];
        acc[n] = mfma16(a[kc], bf, acc[n]);
      }
    }
    #pragma unroll
    for (int n = 0; n < 8; ++n){
      int f = n * 16 + lm;
      #pragma unroll
      for (int i = 0; i < 4; ++i){
        int r = rowbase + lg * 4 + i;
        float val = acc[n][i] + bl[n];
        if (mat == 0){
          Qs[r * ND + f] = f2bf(val * QK_SCALE);
        } else if (mat == 1){
          Ks[r * ND + (f ^ ((r & 7) << 3))] = f2bf(val);
        } else {
          int bb = r >> 12, nt = r & (NT - 1);
          VTs[(bb * ND + f) * NT + (nt ^ ((f & 3) << 3) ^ (((f >> 2) & 1) << 2))] = f2bf(val);
        }
      }
    }
  }
}

// ---------------- kernel 2: flash attention, sq=4 (64 q/wave), kv-halves ----------
// 256 blocks = 128 q-blocks (128 q) x 2 kv-halves (2048 kv). 8 waves = 2 qw (64 q) x
// 4 g (512 kv, 16 tiles of 32). Inner maps identical to R8 (hardware-verified).
// In-block LDS tree-merge of the 4 kv-groups; f32 partials (Op, lp) per half; k_merge.
__global__ __launch_bounds__(512, 2) void k_attn(
    const u16* __restrict__ Qs, const u16* __restrict__ Ks,
    const u16* __restrict__ VTs, float* __restrict__ Op, float* __restrict__ lp)
{
  __shared__ __align__(16) u16 lds[65536];          // 128 KiB (staging; reused for merge)
  __shared__ float lbuf[2][2][64];                  // 1 KiB  (l tree-merge)
  u16* kbuf = lds;                                  // [2][4][32*128]
  u16* vbuf = lds + 32768;                          // [2][4][128*32]

  // XCD-chunked: logical = xcd*32 + j ; qblk = logical&127, half = logical>>7.
  // XCD x hosts 32 consecutive qblks of one half (per-XCD K/V+Q footprint ~2 MB).
  const int lin = blockIdx.x;
  const int logical = (lin & 7) * 32 + (lin >> 3);
  const int qblk = logical & 127;
  const int half = logical >> 7;

  const int lane = threadIdx.x & 63;
  const int w  = threadIdx.x >> 6;
  const int g  = w >> 1, qw = w & 1;                // kv-group, q-wave
  const int lm = lane & 15, lg = lane >> 4;
  const int q0 = qblk * 128 + qw * 64;              // global q base for this wave
  const int b  = q0 >> 12;                          // batch
  const int kv0 = half * 2048 + g * 512;

  // Q frags in registers: rows q0 + sq*16 + lm, k = kc*32 + lg*8 + j  (R8 map)
  s16x8 aq[4][4];
  #pragma unroll
  for (int sq = 0; sq < 4; ++sq){
    const u16* qr = Qs + (size_t)(q0 + sq * 16 + lm) * ND;
    #pragma unroll
    for (int kc = 0; kc < 4; ++kc) aq[sq][kc] = *(const s16x8*)(qr + kc * 32 + lg * 8);
  }

  f32x4 o[4][8];
  #pragma unroll
  for (int sq = 0; sq < 4; ++sq)
    #pragma unroll
    for (int n = 0; n < 8; ++n) o[sq][n] = f32x4{0.f,0.f,0.f,0.f};
  float l_[4] = {0.f, 0.f, 0.f, 0.f};

  // staging pointers (group g covers kv [kv0, kv0+512), 16 tiles of 32)
  const u16* gk = Ks  + ((size_t)b * NT + kv0 + qw * 16 + (lane >> 4)) * ND + (lane & 15) * 8;
  const u16* gv = VTs + ((size_t)b * ND + qw * 64 + (lane >> 2)) * NT + kv0 + (lane & 3) * 8;

  auto stage = [&](int par){
    u16* kd = kbuf + par * 16384 + g * 4096 + qw * 2048;
    u16* vd = vbuf + par * 16384 + g * 4096 + qw * 2048;
    #pragma unroll
    for (int j = 0; j < 4; ++j){
      __builtin_amdgcn_global_load_lds((const as1_void*)(gk + (size_t)j * 4 * ND),
                                       (as3_void*)(kd + j * 512), 16, 0, 0);
      __builtin_amdgcn_global_load_lds((const as1_void*)(gv + (size_t)j * 16 * NT),
                                       (as3_void*)(vd + j * 512), 16, 0, 0);
    }
    gk += (size_t)32 * ND;
    gv += 32;
  };

  stage(0);
  __syncthreads();
  int par = 0;

  const int kswz = (lm & 7) << 3;                           // K b128-read swizzle
  const int vswz = ((lm & 3) << 3) ^ (((lm >> 2) & 1) << 2);// V b64-read swizzle
  const int vcol0 = (lg * 4) ^ vswz;                        // kv lg*4 + {0..3}
  const int vcol1 = (16 + lg * 4) ^ vswz;                   // kv 16+lg*4 + {0..3}

  for (int t = 0; t < 16; ++t){
    if (t < 15) stage(par ^ 1);                 // prefetch next tile
    const u16* kb = kbuf + par * 16384 + g * 4096;
    const u16* vb = vbuf + par * 16384 + g * 4096;

    // ---- S^T = K Q : swapped operands; kf shared across 4 sq ----
    f32x4 st[4][2];
    #pragma unroll
    for (int sq = 0; sq < 4; ++sq)
      #pragma unroll
      for (int n = 0; n < 2; ++n) st[sq][n] = f32x4{0.f,0.f,0.f,0.f};
    __builtin_amdgcn_s_setprio(1);
    #pragma unroll
    for (int kc = 0; kc < 4; ++kc){
      #pragma unroll
      for (int n = 0; n < 2; ++n){
        s16x8 kf = *(const s16x8*)&kb[(n * 16 + lm) * 128 + ((kc * 32 + lg * 8) ^ kswz)];
        #pragma unroll
        for (int sq = 0; sq < 4; ++sq)
          st[sq][n] = mfma16(kf, aq[sq][kc], st[sq][n]);
      }
    }
    __builtin_amdgcn_s_setprio(0);

    // ---- fixed-ref softmax in registers; pack PV A-frags (R8 bijection) ----
    s16x8 pa[4];
    #pragma unroll
    for (int sq = 0; sq < 4; ++sq){
      float p[8];
      #pragma unroll
      for (int n = 0; n < 2; ++n)
        #pragma unroll
        for (int i = 0; i < 4; ++i){
          p[n * 4 + i] = __builtin_amdgcn_exp2f(st[sq][n][i]);
          l_[sq] += p[n * 4 + i];
        }
      pa[sq] = __builtin_bit_cast(s16x8, u32x4{
          cvtpk(p[0], p[1]), cvtpk(p[2], p[3]),
          cvtpk(p[4], p[5]), cvtpk(p[6], p[7])});
    }

    // ---- O += P V : vf = 2x b64 (R8 map); shared across 4 sq ----
    __builtin_amdgcn_s_setprio(1);
    #pragma unroll
    for (int nf = 0; nf < 8; ++nf){
      const int vr = (nf * 16 + lm) * 32;
      u32x2 v0 = *(const u32x2*)&vb[vr + vcol0];
      u32x2 v1 = *(const u32x2*)&vb[vr + vcol1];
      s16x8 vf = __builtin_bit_cast(s16x8, u32x4{v0[0], v0[1], v1[0], v1[1]});
      #pragma unroll
      for (int sq = 0; sq < 4; ++sq)
        o[sq][nf] = mfma16(pa[sq], vf, o[sq][nf]);
    }
    __builtin_amdgcn_s_setprio(0);

    __syncthreads();   // drains prefetch vmcnt + releases buf[par]
    par ^= 1;
  }

  // ---- l: reduce over lg (lanes sharing q) ----
  #pragma unroll
  for (int sq = 0; sq < 4; ++sq){
    float v = l_[sq];
    v += __shfl_xor(v, 16);
    v += __shfl_xor(v, 32);
    l_[sq] = v;                       // all lanes: l for q = sq*16+lm (this g)
  }

  // ---- 3-round LDS tree-merge of the 4 kv-groups (reuse staging LDS) ----
  float* mbF = (float*)lds;           // 4 buffers x [64][128] f32 = 128 KiB
  __syncthreads();                    // all compute done; safe to overwrite
  if (g >= 2){                        // round 1 write: g2->buf[qw], g3->buf[2+qw]
    float* dst = mbF + ((g - 2) * 2 + qw) * 8192;
    #pragma unroll
    for (int sq = 0; sq < 4; ++sq)
      #pragma unroll
      for (int i = 0; i < 4; ++i)
        #pragma unroll
        for (int nf = 0; nf < 8; ++nf)
          dst[(sq * 16 + lg * 4 + i) * 128 + nf * 16 + lm] = o[sq][nf][i];
    if (lg == 0){
      #pragma unroll
      for (int sq = 0; sq < 4; ++sq) lbuf[g - 2][qw][sq * 16 + lm] = l_[sq];
    }
  }
  __syncthreads();
  if (g < 2){                         // round 1 add: g0+=buf[qw](g2), g1+=buf[2+qw](g3)
    const float* src = mbF + (g * 2 + qw) * 8192;
    #pragma unroll
    for (int sq = 0; sq < 4; ++sq){
      #pragma unroll
      for (int i = 0; i < 4; ++i)
        #pragma unroll
        for (int nf = 0; nf < 8; ++nf)
          o[sq][nf][i] += src[(sq * 16 + lg * 4 + i) * 128 + nf * 16 + lm];
      l_[sq] += lbuf[g][qw][sq * 16 + lm];
    }
  }
  __syncthreads();
  if (g == 1){                        // round 2 write: g1 -> buf[qw]
    float* dst = mbF + qw * 8192;
    #pragma unroll
    for (int sq = 0; sq < 4; ++sq)
      #pragma unroll
      for (int i = 0; i < 4; ++i)
        #pragma unroll
        for (int nf = 0; nf < 8; ++nf)
          dst[(sq * 16 + lg * 4 + i) * 128 + nf * 16 + lm] = o[sq][nf][i];
    if (lg == 0){
      #pragma unroll
      for (int sq = 0; sq < 4; ++sq) lbuf[0][qw][sq * 16 + lm] = l_[sq];
    }
  }
  __syncthreads();
  if (g == 0){                        // round 2 add + write partials for this half
    const float* src = mbF + qw * 8192;
    #pragma unroll
    for (int sq = 0; sq < 4; ++sq){
      l_[sq] += lbuf[0][qw][sq * 16 + lm];
      #pragma unroll
      for (int i = 0; i < 4; ++i){
        const size_t r = (size_t)half * NQ + q0 + sq * 16 + lg * 4 + i;
        #pragma unroll
        for (int nf = 0; nf < 8; ++nf)
          Op[r * ND + nf * 16 + lm] =
              o[sq][nf][i] + src[(sq * 16 + lg * 4 + i) * 128 + nf * 16 + lm];
      }
      if (lg == 0) lp[(size_t)half * NQ + q0 + sq * 16 + lm] = l_[sq];
    }
  }
}

// ---------------- kernel 3: merge kv-halves + normalize ----------------
__global__ __launch_bounds__(256) void k_merge(const float* __restrict__ Op,
                                               const float* __restrict__ lp,
                                               float* __restrict__ Out){
  const int gid = blockIdx.x * 256 + threadIdx.x;   // over NQ*32 float4 chunks
  const int q = gid >> 5, c = gid & 31;
  f32x4 a = *(const f32x4*)(Op + (size_t)q * ND + c * 4);
  f32x4 d = *(const f32x4*)(Op + ((size_t)NQ + q) * ND + c * 4);
  const float inv = 1.f / (lp[q] + lp[NQ + q]);
  f32x4 r;
  r[0] = (a[0] + d[0]) * inv; r[1] = (a[1] + d[1]) * inv;
  r[2] = (a[2] + d[2]) * inv; r[3] = (a[3] + d[3]) * inv;
  *(f32x4*)(Out + (size_t)q * ND + c * 4) = r;
}

extern "C" void kernel_launch(void* const* d_in, const int* in_sizes, int n_in,
                              void* d_out, int out_size, void* d_ws, size_t ws_size,
                              hipStream_t stream) {
  const float* X  = (const float*)d_in[0];
  const float* Wq = (const float*)d_in[1];
  const float* bq = (const float*)d_in[2];
  const float* Wk = (const float*)d_in[3];
  const float* bk = (const float*)d_in[4];
  const float* Wv = (const float*)d_in[5];
  const float* bv = (const float*)d_in[6];
  float* Out = (float*)d_out;

  u16* Qs  = (u16*)d_ws;                        // 4 MiB
  u16* Ks  = Qs  + (size_t)NQ * ND;             // 4 MiB
  u16* VTs = Ks  + (size_t)NQ * ND;             // 4 MiB
  u16* WT  = VTs + (size_t)NQ * ND;             // 96 KiB
  float* Op = (float*)(WT + 3 * 128 * 128);     // 16 MiB  (2 halves)
  float* lp = Op + (size_t)2 * NQ * ND;         // 128 KiB

  hipLaunchKernelGGL(k_wprep, dim3(3 * 128), dim3(128), 0, stream, Wq, Wk, Wv, WT);
  hipLaunchKernelGGL(k_proj,  dim3(NQ / 64), dim3(256), 0, stream,
                     X, WT, bq, bk, bv, Qs, Ks, VTs);
  hipLaunchKernelGGL(k_attn,  dim3(256), dim3(512), 0, stream, Qs, Ks, VTs, Op, lp);
  hipLaunchKernelGGL(k_merge, dim3(NQ * 32 / 256), dim3(256), 0, stream, Op, lp, Out);
}